// Round 1
// baseline (385.996 us; speedup 1.0000x reference)
//
#include <hip/hip_runtime.h>
#include <math.h>

#define EPS 1e-6f
constexpr int N_ = 4, L_ = 4096, H_ = 16, D_ = 64;
constexpr int NH = N_ * H_;             // 64
constexpr int HD = H_ * D_;             // 1024 floats per (n,l) row = 4KB
constexpr long NSTRIDE = (long)L_ * HD; // 4194304
constexpr int SCHUNKS = 32;             // s-chunks of 128 rows for kv partials

// Scratch device globals. Accumulators zeroed by k0 each call; everything
// else fully written before read each call (graph-replay safe).
__device__ float g_qsum[NH * D_];
__device__ float g_ksum[NH * D_];
__device__ float g_qnr[NH * D_];
__device__ float g_knc[NH * D_];
__device__ float g_ssum[NH];
__device__ float g_kv[NH * D_ * D_];
__device__ float g_kvpart[(long)SCHUNKS * NH * D_ * D_];  // 32 MB

__device__ __forceinline__ float sigm(float x) {
    return 1.0f / (1.0f + __expf(-x));
}
__device__ __forceinline__ float4 sigm4(float4 x) {
    float4 r;
    r.x = sigm(x.x); r.y = sigm(x.y); r.z = sigm(x.z); r.w = sigm(x.w);
    return r;
}
// sum across the 16-lane group (lanes grouped by t&~15); xor masks < 16
// stay inside the group. All callers have all lanes of the group active.
__device__ __forceinline__ float red16(float p) {
    p += __shfl_xor(p, 1);
    p += __shfl_xor(p, 2);
    p += __shfl_xor(p, 4);
    p += __shfl_xor(p, 8);
    return p;
}

// ---------------- k0: zero accumulators ----------------
__global__ void k0_zero() {
    int i = blockIdx.x * blockDim.x + threadIdx.x;
    int st = gridDim.x * blockDim.x;
    for (int j = i; j < NH * D_; j += st) {
        g_qsum[j] = 0.f; g_ksum[j] = 0.f; g_qnr[j] = 0.f; g_knc[j] = 0.f;
    }
    for (int j = i; j < NH; j += st) g_ssum[j] = 0.f;
}

// ---------------- k1: q_sum / k_sum, fully contiguous ----------------
// Block reads 32 consecutive (n,l) rows of 4KB: 1KB per wave per load.
// Thread t permanently owns (h = t>>4, d-quad = t&15) -> register acc,
// one atomic float4 tail per thread.
__global__ __launch_bounds__(256) void k1_sums(const float* __restrict__ q,
                                               const float* __restrict__ k) {
    const float* src = blockIdx.z ? k : q;
    float* dst = blockIdx.z ? g_ksum : g_qsum;
    int t = threadIdx.x;
    long g0 = (long)blockIdx.x * 32;    // global row in [0, N_*L_)
    int n = (int)(g0 >> 12);            // 32 | 4096, so n constant in block
    const float* p = src + g0 * HD + t * 4;
    float ax = 0.f, ay = 0.f, az = 0.f, aw = 0.f;
#pragma unroll 8
    for (int r = 0; r < 32; ++r) {
        float4 x = *(const float4*)(p + (long)r * HD);
        float4 s = sigm4(x);
        ax += s.x; ay += s.y; az += s.z; aw += s.w;
    }
    float* d0 = dst + n * 1024 + t * 4;   // n*H*D + h*64 + c4*4 == n*1024 + t*4
    atomicAdd(d0 + 0, ax);
    atomicAdd(d0 + 1, ay);
    atomicAdd(d0 + 2, az);
    atomicAdd(d0 + 3, aw);
}

// ---------------- k2: normalizers + qnr/knc, fused both sides ----------------
// Row side (z=0, q, bvec=ksum): nr_l = 1/dot, qnr += sig(q)*nr.
// Col side (z=1, k, bvec=qsum): nc_s = 1/dot, knc += sig(k)*nc.
// Same contiguous layout as k1; per-row dot closed by a 16-lane shfl reduce.
// nr itself is NOT stored -- k5 recomputes it from ksum (saves 32MiB traffic).
__global__ __launch_bounds__(256) void k2_norm(const float* __restrict__ q,
                                               const float* __restrict__ k) {
    bool col = blockIdx.z != 0;
    const float* src = col ? k : q;
    const float* sums = col ? g_qsum : g_ksum;
    float* acc = col ? g_knc : g_qnr;
    int t = threadIdx.x;
    long g0 = (long)blockIdx.x * 32;
    int n = (int)(g0 >> 12);
    float4 bv = *(const float4*)(sums + n * 1024 + t * 4);
    bv.x += EPS; bv.y += EPS; bv.z += EPS; bv.w += EPS;
    const float* p = src + g0 * HD + t * 4;
    float ax = 0.f, ay = 0.f, az = 0.f, aw = 0.f;
#pragma unroll 4
    for (int r = 0; r < 32; ++r) {
        float4 x = *(const float4*)(p + (long)r * HD);
        float4 s = sigm4(x);
        float pd = (s.x + EPS) * bv.x + (s.y + EPS) * bv.y
                 + (s.z + EPS) * bv.z + (s.w + EPS) * bv.w;
        pd = red16(pd);               // full 64-d dot for this row's head
        float inv = 1.0f / pd;
        ax += s.x * inv; ay += s.y * inv; az += s.z * inv; aw += s.w * inv;
    }
    float* d0 = acc + n * 1024 + t * 4;
    atomicAdd(d0 + 0, ax);
    atomicAdd(d0 + 1, ay);
    atomicAdd(d0 + 2, az);
    atomicAdd(d0 + 3, aw);
}

// ---------------- k3_kv: fused col_refine + exp + ssum + fp32 kv partials ----
// Per (s-chunk of 128, nh). Stages sig(k) and v tiles, computes
// cr_s = (sig(k)+EPS).(qnr+EPS) during staging, e_s = exp(cr_s) (softmax is
// shift-invariant; cr = O(1) for these inputs so no max pass needed),
// accumulates ssum atomically, pre-scales the k-tile by e_s, then an exact
// fp32 outer-product GEMM (4x4 regs/thread, 2048 FMA) -> kv partial.
// Replaces the old k3-col + k3b + split3-bf16 MFMA k4 entirely.
__global__ __launch_bounds__(256) void k3_kv(const float* __restrict__ k,
                                             const float* __restrict__ v) {
    int nh = blockIdx.y, n = nh >> 4, h = nh & 15;
    int t = threadIdx.x;
    __shared__ float ktile[128 * 64];
    __shared__ float vtile[128 * 64];
    __shared__ float pbuf[128];
    __shared__ float redb[128];
    __shared__ float qnrbuf[64];
    if (t < 16) {
        float4 w = *(const float4*)&g_qnr[nh * 64 + t * 4];
        w.x += EPS; w.y += EPS; w.z += EPS; w.w += EPS;
        *(float4*)&qnrbuf[t * 4] = w;
    }
    __syncthreads();
    int rb = t >> 4, c4 = t & 15;
    float4 qn = *(const float4*)&qnrbuf[c4 * 4];
    long nbase = (long)n * NSTRIDE + (long)h * D_;
    int s0 = blockIdx.x * 128;
#pragma unroll
    for (int j = 0; j < 8; ++j) {
        int r = rb + j * 16;
        long gi = nbase + (long)(s0 + r) * HD + c4 * 4;
        float4 kk = *(const float4*)&k[gi];
        float4 vv = *(const float4*)&v[gi];
        float4 sk = sigm4(kk);
        *(float4*)&ktile[r * 64 + c4 * 4] = sk;
        *(float4*)&vtile[r * 64 + c4 * 4] = vv;
        float pd = (sk.x + EPS) * qn.x + (sk.y + EPS) * qn.y
                 + (sk.z + EPS) * qn.z + (sk.w + EPS) * qn.w;
        pd = red16(pd);
        if (c4 == 0) pbuf[r] = pd;
    }
    __syncthreads();
    if (t < 128) {
        float e = __expf(pbuf[t]);
        pbuf[t] = e;
        redb[t] = e;
    }
    __syncthreads();
    if (t < 64) redb[t] += redb[t + 64];
    __syncthreads();
    if (t < 16) {
        float s = redb[t] + redb[t + 16] + redb[t + 32] + redb[t + 48];
        s = red16(s);
        if (t == 0) atomicAdd(&g_ssum[nh], s);
    }
    // pre-scale k-tile rows by e_s (pbuf final since last sync)
#pragma unroll
    for (int j = 0; j < 8; ++j) {
        int r = rb + j * 16;
        float e = pbuf[r];
        float4 kk = *(float4*)&ktile[r * 64 + c4 * 4];
        kk.x *= e; kk.y *= e; kk.z *= e; kk.w *= e;
        *(float4*)&ktile[r * 64 + c4 * 4] = kk;
    }
    __syncthreads();
    // exact fp32 GEMM: thread (dq,eq) owns d=dq*4..+4, e=eq*4..+4.
    // LDS reads: k4 has 4 unique addrs/wave (conflict-free), v4 has 16
    // unique 16B addrs = exactly 2-deep/bank (free).
    int dq = t >> 4, eq = t & 15;
    float acc[4][4];
#pragma unroll
    for (int r = 0; r < 4; ++r)
#pragma unroll
        for (int c = 0; c < 4; ++c) acc[r][c] = 0.f;
#pragma unroll 4
    for (int s = 0; s < 128; ++s) {
        float4 k4 = *(const float4*)&ktile[s * 64 + dq * 4];
        float4 v4 = *(const float4*)&vtile[s * 64 + eq * 4];
        acc[0][0] += k4.x * v4.x; acc[0][1] += k4.x * v4.y;
        acc[0][2] += k4.x * v4.z; acc[0][3] += k4.x * v4.w;
        acc[1][0] += k4.y * v4.x; acc[1][1] += k4.y * v4.y;
        acc[1][2] += k4.y * v4.z; acc[1][3] += k4.y * v4.w;
        acc[2][0] += k4.z * v4.x; acc[2][1] += k4.z * v4.y;
        acc[2][2] += k4.z * v4.z; acc[2][3] += k4.z * v4.w;
        acc[3][0] += k4.w * v4.x; acc[3][1] += k4.w * v4.y;
        acc[3][2] += k4.w * v4.z; acc[3][3] += k4.w * v4.w;
    }
    float* dst = &g_kvpart[((long)blockIdx.x * NH + nh) * 4096];
#pragma unroll
    for (int r = 0; r < 4; ++r) {
        float4 o = {acc[r][0], acc[r][1], acc[r][2], acc[r][3]};
        *(float4*)&dst[(dq * 4 + r) * 64 + eq * 4] = o;
    }
}

// ---------------- k4b: reduce kv partials, apply softmax scale ----------------
__global__ __launch_bounds__(256) void k4b_reduce() {
    int nh = blockIdx.x;
    int i4 = blockIdx.y * 256 + threadIdx.x;   // float4 index 0..1023
    float sx = 0.f, sy = 0.f, sz = 0.f, sw = 0.f;
#pragma unroll 8
    for (int c = 0; c < SCHUNKS; ++c) {
        float4 p = *(const float4*)&g_kvpart[((long)c * NH + nh) * 4096 + i4 * 4];
        sx += p.x; sy += p.y; sz += p.z; sw += p.w;
    }
    float scale = (float)L_ / g_ssum[nh];      // S * e_s / sum(e)
    float4 o = {sx * scale, sy * scale, sz * scale, sw * scale};
    *(float4*)&g_kv[nh * 4096 + i4 * 4] = o;
}

// ---------------- k5: inline coefrow + out = (sig(q)@kv)*coef ----------------
// coefrow recomputed from the staged sig(q) tile: nr = 1/((s+EPS).(ksum+EPS)),
// rowref = sigm((s+EPS).(knc+EPS))  [L/S == 1], coef = rowref/denom.
// Eliminates the old k3 row-side pass over q entirely.
__global__ __launch_bounds__(256) void k5_out(const float* __restrict__ q,
                                              float* __restrict__ out) {
    int nh = blockIdx.y, n = nh >> 4, h = nh & 15;
    int t = threadIdx.x;
    __shared__ float kvt[64 * 64];
    __shared__ float qt[64][65];
    __shared__ float coef[64];
    __shared__ float bk1[64], bk2[64];
    if (t < 16) {
        float4 a = *(const float4*)&g_ksum[nh * 64 + t * 4];
        a.x += EPS; a.y += EPS; a.z += EPS; a.w += EPS;
        *(float4*)&bk1[t * 4] = a;
        float4 b = *(const float4*)&g_knc[nh * 64 + t * 4];
        b.x += EPS; b.y += EPS; b.z += EPS; b.w += EPS;
        *(float4*)&bk2[t * 4] = b;
    }
#pragma unroll
    for (int j = 0; j < 4; ++j)
        *(float4*)&kvt[(t + j * 256) * 4] =
            *(const float4*)&g_kv[nh * 4096 + (t + j * 256) * 4];
    __syncthreads();
    int c4 = t & 15, rg = t >> 4;
    float4 b1 = *(const float4*)&bk1[c4 * 4];
    float4 b2 = *(const float4*)&bk2[c4 * 4];
    int l0 = blockIdx.x * 64;
    long nbase = (long)n * NSTRIDE + (long)h * D_;
#pragma unroll
    for (int j = 0; j < 4; ++j) {
        int r = rg + j * 16;
        float4 x = *(const float4*)&q[nbase + (long)(l0 + r) * HD + c4 * 4];
        float4 s = sigm4(x);
        qt[r][c4 * 4 + 0] = s.x;
        qt[r][c4 * 4 + 1] = s.y;
        qt[r][c4 * 4 + 2] = s.z;
        qt[r][c4 * 4 + 3] = s.w;
        float p1 = (s.x + EPS) * b1.x + (s.y + EPS) * b1.y
                 + (s.z + EPS) * b1.z + (s.w + EPS) * b1.w;
        float p2 = (s.x + EPS) * b2.x + (s.y + EPS) * b2.y
                 + (s.z + EPS) * b2.z + (s.w + EPS) * b2.w;
        p1 = red16(p1);
        p2 = red16(p2);
        if (c4 == 0) coef[r] = sigm(p2) / p1;
    }
    __syncthreads();
    int e4 = t & 15, lg = t >> 4;
    float acc[4][4];
#pragma unroll
    for (int r = 0; r < 4; ++r)
#pragma unroll
        for (int c = 0; c < 4; ++c) acc[r][c] = 0.f;
#pragma unroll 8
    for (int d = 0; d < 64; ++d) {
        float4 kvv = *(const float4*)&kvt[d * 64 + e4 * 4];
#pragma unroll
        for (int r = 0; r < 4; ++r) {
            float qv = qt[lg * 4 + r][d];
            acc[r][0] += qv * kvv.x;
            acc[r][1] += qv * kvv.y;
            acc[r][2] += qv * kvv.z;
            acc[r][3] += qv * kvv.w;
        }
    }
#pragma unroll
    for (int r = 0; r < 4; ++r) {
        int l = l0 + lg * 4 + r;
        float cf = coef[lg * 4 + r];
        float4 o = {acc[r][0] * cf, acc[r][1] * cf, acc[r][2] * cf, acc[r][3] * cf};
        *(float4*)&out[nbase + (long)l * HD + e4 * 4] = o;
    }
}

extern "C" void kernel_launch(void* const* d_in, const int* in_sizes, int n_in,
                              void* d_out, int out_size, void* d_ws, size_t ws_size,
                              hipStream_t stream) {
    const float* q = (const float*)d_in[0];
    const float* k = (const float*)d_in[1];
    const float* v = (const float*)d_in[2];
    float* out = (float*)d_out;

    k0_zero<<<64, 256, 0, stream>>>();
    k1_sums<<<dim3(512, 1, 2), 256, 0, stream>>>(q, k);
    k2_norm<<<dim3(512, 1, 2), 256, 0, stream>>>(q, k);
    k3_kv<<<dim3(SCHUNKS, NH), 256, 0, stream>>>(k, v);
    k4b_reduce<<<dim3(NH, 4), 256, 0, stream>>>();
    k5_out<<<dim3(L_ / 64, NH), 256, 0, stream>>>(q, out);
}

// Round 2
// 292.532 us; speedup vs baseline: 1.3195x; 1.3195x over previous
//
#include <hip/hip_runtime.h>
#include <math.h>

#define EPS 1e-6f
constexpr int N_ = 4, L_ = 4096, H_ = 16, D_ = 64;
constexpr int NH = N_ * H_;             // 64
constexpr int HD = H_ * D_;             // 1024 floats per (n,l) row
constexpr long NSTRIDE = (long)L_ * HD;
constexpr int SCHUNKS = 16;             // 256 s-rows per kv chunk
constexpr int K1B = 1024;               // blocks per tensor-side in k1/k2 (16 rows each)

typedef __attribute__((ext_vector_type(8))) short short8;
typedef __attribute__((ext_vector_type(4))) float f32x4;

// Scratch device globals. Everything fully written before read each call
// (graph-replay safe); g_ssum zeroed by kred(0) each call.
__device__ float g_qsum[NH * D_];
__device__ float g_ksum[NH * D_];
__device__ float g_qnr[NH * D_];
__device__ float g_knc[NH * D_];
__device__ float g_ssum[NH];
__device__ float g_kv[NH * D_ * D_];
__device__ float g_kvpart[(long)SCHUNKS * NH * D_ * D_];  // 16 MB
__device__ float g_part[2 * K1B * 1024];                  // 8 MB block partials

__device__ __forceinline__ float sigm(float x) {
    return 1.0f / (1.0f + __expf(-x));
}
__device__ __forceinline__ float4 sigm4(float4 x) {
    float4 r;
    r.x = sigm(x.x); r.y = sigm(x.y); r.z = sigm(x.z); r.w = sigm(x.w);
    return r;
}
// sum across the 16-lane group (xor masks < 16 stay inside the group)
__device__ __forceinline__ float red16(float p) {
    p += __shfl_xor(p, 1);
    p += __shfl_xor(p, 2);
    p += __shfl_xor(p, 4);
    p += __shfl_xor(p, 8);
    return p;
}
// RNE round of fp32 bits to bf16, returned high-16-aligned
__device__ __forceinline__ unsigned rne_hi(unsigned xb) {
    return (xb + 0x7fffu + ((xb >> 16) & 1u)) & 0xffff0000u;
}
// exact-ish split: x ~= h1 + h2 (each bf16), residual <= 2^-17 |x|
__device__ __forceinline__ uint2 split2(float x) {
    unsigned h1 = rne_hi(__float_as_uint(x));
    float r = x - __uint_as_float(h1);
    unsigned h2 = rne_hi(__float_as_uint(r));
    return make_uint2(h1, h2);
}
union U8 { unsigned u[4]; short8 s; };

// ---------------- k1: q_sum / k_sum partials (contiguous rows) ----------------
__global__ __launch_bounds__(256) void k1_sums(const float* __restrict__ q,
                                               const float* __restrict__ k) {
    const float* src = blockIdx.z ? k : q;
    int t = threadIdx.x;
    long g0 = (long)blockIdx.x * 16;     // 16 consecutive (n,l) rows
    const float* p = src + g0 * HD + t * 4;
    float ax = 0.f, ay = 0.f, az = 0.f, aw = 0.f;
#pragma unroll
    for (int r = 0; r < 16; ++r) {
        float4 x = *(const float4*)(p + (long)r * HD);
        float4 s = sigm4(x);
        ax += s.x; ay += s.y; az += s.z; aw += s.w;
    }
    float4 o = {ax, ay, az, aw};
    *(float4*)&g_part[((blockIdx.z * K1B + blockIdx.x) << 10) + t * 4] = o;
}

// ---------------- k2: qnr / knc partials ----------------
__global__ __launch_bounds__(256) void k2_norm(const float* __restrict__ q,
                                               const float* __restrict__ k) {
    bool col = blockIdx.z != 0;
    const float* src = col ? k : q;
    const float* sums = col ? g_qsum : g_ksum;
    int t = threadIdx.x;
    long g0 = (long)blockIdx.x * 16;
    int n = (int)(g0 >> 12);
    float4 bv = *(const float4*)(sums + n * 1024 + t * 4);
    bv.x += EPS; bv.y += EPS; bv.z += EPS; bv.w += EPS;
    const float* p = src + g0 * HD + t * 4;
    float ax = 0.f, ay = 0.f, az = 0.f, aw = 0.f;
#pragma unroll 4
    for (int r = 0; r < 16; ++r) {
        float4 x = *(const float4*)(p + (long)r * HD);
        float4 s = sigm4(x);
        float pd = (s.x + EPS) * bv.x + (s.y + EPS) * bv.y
                 + (s.z + EPS) * bv.z + (s.w + EPS) * bv.w;
        pd = red16(pd);                    // full 64-d dot for this row
        float inv = 1.0f / pd;
        ax += s.x * inv; ay += s.y * inv; az += s.z * inv; aw += s.w * inv;
    }
    float4 o = {ax, ay, az, aw};
    *(float4*)&g_part[((blockIdx.z * K1B + blockIdx.x) << 10) + t * 4] = o;
}

// ---------------- kred: tree-reduce partials; which=0 -> sums, 1 -> nr/nc ----
__global__ __launch_bounds__(256) void kred(int which) {
    int bid = blockIdx.x, t = threadIdx.x;
    int z = bid & 1, n = (bid >> 1) & 3, cc = bid >> 3;   // 2 x 4 x 8 = 64 blocks
    int c = cc * 128 + (t & 31) * 4;
    int bg = t >> 5;                                       // 0..7
    float sx = 0.f, sy = 0.f, sz = 0.f, sw = 0.f;
#pragma unroll 4
    for (int i = 0; i < 32; ++i) {
        int b = n * 256 + bg * 32 + i;
        const float* pp = &g_part[((z * K1B + b) << 10) + c];
        float4 p = *(const float4*)pp;
        sx += p.x; sy += p.y; sz += p.z; sw += p.w;
    }
    __shared__ float4 esb[256];
    esb[t] = make_float4(sx, sy, sz, sw);
    __syncthreads();
    if (t < 32) {
        float4 s = esb[t];
#pragma unroll
        for (int g = 1; g < 8; ++g) {
            float4 b = esb[t + g * 32];
            s.x += b.x; s.y += b.y; s.z += b.z; s.w += b.w;
        }
        float* dst = which ? (z ? g_knc : g_qnr) : (z ? g_ksum : g_qsum);
        *(float4*)&dst[n * 1024 + cc * 128 + t * 4] = s;
    }
    if (which == 0 && bid == 0 && t < NH) g_ssum[t] = 0.f;
}

// ---------------- k4: fused col_refine+exp+ssum + split2-bf16 MFMA kv ---------
// LDS planes: u32 word at [s-pair][col] = {lo16 = bf16(even s), hi16 = bf16(odd s)}
// kA/kB = split1/split2 of sig(k)*e_s ; vA/vB = split1/split2 of v.
// MFMA frags assemble from 4 ds_read_b32 each, zero unpack VALU.
__global__ __launch_bounds__(256, 4) void k4_kv(const float* __restrict__ k,
                                                const float* __restrict__ v) {
    int nh = blockIdx.y, n = nh >> 4, h = nh & 15;
    int t = threadIdx.x, lane = t & 63, wv = t >> 6;
    __shared__ unsigned kA[16 * 66], kB[16 * 66], vA[16 * 66], vB[16 * 66];
    __shared__ float esb[256];
    int sp = t >> 4, c4 = t & 15;
    long nbase = (long)n * NSTRIDE + (long)h * D_;
    int s0blk = blockIdx.x * 256;
    float4 qn = *(const float4*)&g_qnr[nh * 64 + c4 * 4];
    qn.x += EPS; qn.y += EPS; qn.z += EPS; qn.w += EPS;

    f32x4 acc[4];
#pragma unroll
    for (int e = 0; e < 4; ++e) acc[e] = (f32x4){0.f, 0.f, 0.f, 0.f};
    int m = lane & 15, qd = lane >> 4;
    float esum = 0.f;

    float4 ke, ko, ve, vo;
    {
        long gb = nbase + (long)(s0blk + 2 * sp) * HD + c4 * 4;
        ke = *(const float4*)&k[gb]; ko = *(const float4*)&k[gb + HD];
        ve = *(const float4*)&v[gb]; vo = *(const float4*)&v[gb + HD];
    }
    for (int st = 0; st < 8; ++st) {
        // ---- sigm + cr dot + exp + scale + pack (registers only)
        float4 se = sigm4(ke), so = sigm4(ko);
        float pde = (se.x + EPS) * qn.x + (se.y + EPS) * qn.y
                  + (se.z + EPS) * qn.z + (se.w + EPS) * qn.w;
        float pdo = (so.x + EPS) * qn.x + (so.y + EPS) * qn.y
                  + (so.z + EPS) * qn.z + (so.w + EPS) * qn.w;
        pde = red16(pde); pdo = red16(pdo);
        float ee = __expf(pde), eo = __expf(pdo);
        if (c4 == 0) esum += ee + eo;
        se.x *= ee; se.y *= ee; se.z *= ee; se.w *= ee;
        so.x *= eo; so.y *= eo; so.z *= eo; so.w *= eo;
        uint2 a0 = split2(se.x), a1_ = split2(se.y), a2_ = split2(se.z), a3_ = split2(se.w);
        uint2 b0 = split2(so.x), b1_ = split2(so.y), b2_ = split2(so.z), b3_ = split2(so.w);
        unsigned kaw0 = (a0.x >> 16) | (b0.x & 0xffff0000u);
        unsigned kaw1 = (a1_.x >> 16) | (b1_.x & 0xffff0000u);
        unsigned kaw2 = (a2_.x >> 16) | (b2_.x & 0xffff0000u);
        unsigned kaw3 = (a3_.x >> 16) | (b3_.x & 0xffff0000u);
        unsigned kbw0 = (a0.y >> 16) | (b0.y & 0xffff0000u);
        unsigned kbw1 = (a1_.y >> 16) | (b1_.y & 0xffff0000u);
        unsigned kbw2 = (a2_.y >> 16) | (b2_.y & 0xffff0000u);
        unsigned kbw3 = (a3_.y >> 16) | (b3_.y & 0xffff0000u);
        uint2 c0 = split2(ve.x), c1 = split2(ve.y), c2 = split2(ve.z), c3 = split2(ve.w);
        uint2 d0 = split2(vo.x), d1 = split2(vo.y), d2 = split2(vo.z), d3 = split2(vo.w);
        unsigned vaw0 = (c0.x >> 16) | (d0.x & 0xffff0000u);
        unsigned vaw1 = (c1.x >> 16) | (d1.x & 0xffff0000u);
        unsigned vaw2 = (c2.x >> 16) | (d2.x & 0xffff0000u);
        unsigned vaw3 = (c3.x >> 16) | (d3.x & 0xffff0000u);
        unsigned vbw0 = (c0.y >> 16) | (d0.y & 0xffff0000u);
        unsigned vbw1 = (c1.y >> 16) | (d1.y & 0xffff0000u);
        unsigned vbw2 = (c2.y >> 16) | (d2.y & 0xffff0000u);
        unsigned vbw3 = (c3.y >> 16) | (d3.y & 0xffff0000u);
        __syncthreads();   // prior MFMA reads done
        int wb = sp * 66 + c4 * 4;
        *(uint2*)&kA[wb] = make_uint2(kaw0, kaw1); *(uint2*)&kA[wb + 2] = make_uint2(kaw2, kaw3);
        *(uint2*)&kB[wb] = make_uint2(kbw0, kbw1); *(uint2*)&kB[wb + 2] = make_uint2(kbw2, kbw3);
        *(uint2*)&vA[wb] = make_uint2(vaw0, vaw1); *(uint2*)&vA[wb + 2] = make_uint2(vaw2, vaw3);
        *(uint2*)&vB[wb] = make_uint2(vbw0, vbw1); *(uint2*)&vB[wb + 2] = make_uint2(vbw2, vbw3);
        __syncthreads();
        if (st < 7) {      // prefetch next subtile under the MFMA phase
            long gb = nbase + (long)(s0blk + (st + 1) * 32 + 2 * sp) * HD + c4 * 4;
            ke = *(const float4*)&k[gb]; ko = *(const float4*)&k[gb + HD];
            ve = *(const float4*)&v[gb]; vo = *(const float4*)&v[gb + HD];
        }
        // ---- MFMA: one K=32 step over these 32 s-rows
        U8 fa1, fa2;
#pragma unroll
        for (int jp = 0; jp < 4; ++jp) {
            int idx = (qd * 4 + jp) * 66 + wv * 16 + m;
            fa1.u[jp] = kA[idx]; fa2.u[jp] = kB[idx];
        }
#pragma unroll
        for (int e = 0; e < 4; ++e) {
            U8 fb1, fb2;
#pragma unroll
            for (int jp = 0; jp < 4; ++jp) {
                int idx = (qd * 4 + jp) * 66 + e * 16 + m;
                fb1.u[jp] = vA[idx]; fb2.u[jp] = vB[idx];
            }
            acc[e] = __builtin_amdgcn_mfma_f32_16x16x32_bf16(fa1.s, fb2.s, acc[e], 0, 0, 0);
            acc[e] = __builtin_amdgcn_mfma_f32_16x16x32_bf16(fa2.s, fb1.s, acc[e], 0, 0, 0);
            acc[e] = __builtin_amdgcn_mfma_f32_16x16x32_bf16(fa1.s, fb1.s, acc[e], 0, 0, 0);
        }
    }
    // epilogue: C/D layout col=lane&15, row=qd*4+reg; wave wv owns d-strip
    float* dst = &g_kvpart[((long)blockIdx.x * NH + nh) * 4096];
#pragma unroll
    for (int e = 0; e < 4; ++e)
#pragma unroll
        for (int r = 0; r < 4; ++r)
            dst[(wv * 16 + qd * 4 + r) * 64 + e * 16 + m] = acc[e][r];
    esb[t] = esum;
    __syncthreads();
    for (int s = 128; s; s >>= 1) {
        if (t < s) esb[t] += esb[t + s];
        __syncthreads();
    }
    if (t == 0) atomicAdd(&g_ssum[nh], esb[0]);
}

// ---------------- k4b: reduce kv partials, apply softmax scale ----------------
__global__ __launch_bounds__(256) void k4b_reduce() {
    int nh = blockIdx.x;
    int i4 = blockIdx.y * 256 + threadIdx.x;   // float4 index 0..1023
    float sx = 0.f, sy = 0.f, sz = 0.f, sw = 0.f;
#pragma unroll
    for (int c = 0; c < SCHUNKS; ++c) {
        float4 p = *(const float4*)&g_kvpart[((long)c * NH + nh) * 4096 + i4 * 4];
        sx += p.x; sy += p.y; sz += p.z; sw += p.w;
    }
    float scale = (float)L_ / g_ssum[nh];
    float4 o = {sx * scale, sy * scale, sz * scale, sw * scale};
    *(float4*)&g_kv[nh * 4096 + i4 * 4] = o;
}

// ---------------- k5: inline coef + split2-bf16 MFMA out = sig(q)@kv * coef ---
// q planes: [d-pair][l] ; kv planes: [d-pair][e]. Same frag math as k4.
__global__ __launch_bounds__(256, 4) void k5_out(const float* __restrict__ q,
                                                 float* __restrict__ out) {
    int nh = blockIdx.y, n = nh >> 4, h = nh & 15;
    int t = threadIdx.x, lane = t & 63, wv = t >> 6;
    __shared__ unsigned qA[32 * 66], qB[32 * 66], kvA[32 * 66], kvB[32 * 66];
    __shared__ float coef[64];
    int c4 = t & 15;
    long nbase = (long)n * NSTRIDE + (long)h * D_;
    int l0 = blockIdx.x * 64;
    float4 bk1 = *(const float4*)&g_ksum[nh * 64 + c4 * 4];
    float4 bk2 = *(const float4*)&g_knc[nh * 64 + c4 * 4];
    bk1.x += EPS; bk1.y += EPS; bk1.z += EPS; bk1.w += EPS;
    bk2.x += EPS; bk2.y += EPS; bk2.z += EPS; bk2.w += EPS;
    // stage kv (pair-packed over d)
#pragma unroll
    for (int j = 0; j < 2; ++j) {
        int slot = t + j * 256;
        int dp = slot >> 4, cc = slot & 15;
        const float* kvr = &g_kv[nh * 4096 + (2 * dp) * 64 + cc * 4];
        float4 xe = *(const float4*)kvr;
        float4 xo = *(const float4*)(kvr + 64);
        uint2 e0 = split2(xe.x), e1 = split2(xe.y), e2 = split2(xe.z), e3 = split2(xe.w);
        uint2 o0 = split2(xo.x), o1 = split2(xo.y), o2 = split2(xo.z), o3 = split2(xo.w);
        int wb = dp * 66 + cc * 4;
        *(uint2*)&kvA[wb] = make_uint2((e0.x >> 16) | (o0.x & 0xffff0000u),
                                       (e1.x >> 16) | (o1.x & 0xffff0000u));
        *(uint2*)&kvA[wb + 2] = make_uint2((e2.x >> 16) | (o2.x & 0xffff0000u),
                                           (e3.x >> 16) | (o3.x & 0xffff0000u));
        *(uint2*)&kvB[wb] = make_uint2((e0.y >> 16) | (o0.y & 0xffff0000u),
                                       (e1.y >> 16) | (o1.y & 0xffff0000u));
        *(uint2*)&kvB[wb + 2] = make_uint2((e2.y >> 16) | (o2.y & 0xffff0000u),
                                           (e3.y >> 16) | (o3.y & 0xffff0000u));
    }
    // stage q (pair-packed over d, transposed to [dp][l]) + coef
#pragma unroll
    for (int j = 0; j < 4; ++j) {
        int slot = t + j * 256;
        int r = slot >> 4;                  // l-local 0..63 ; col quad == c4
        float4 x = *(const float4*)&q[nbase + (long)(l0 + r) * HD + c4 * 4];
        float4 s = sigm4(x);
        float p1 = (s.x + EPS) * bk1.x + (s.y + EPS) * bk1.y
                 + (s.z + EPS) * bk1.z + (s.w + EPS) * bk1.w;
        float p2 = (s.x + EPS) * bk2.x + (s.y + EPS) * bk2.y
                 + (s.z + EPS) * bk2.z + (s.w + EPS) * bk2.w;
        p1 = red16(p1); p2 = red16(p2);
        if (c4 == 0) coef[r] = sigm(p2) / p1;
        uint2 t0 = split2(s.x), t1 = split2(s.y), t2 = split2(s.z), t3 = split2(s.w);
        qA[(c4 * 2) * 66 + r]     = (t0.x >> 16) | (t1.x & 0xffff0000u);
        qB[(c4 * 2) * 66 + r]     = (t0.y >> 16) | (t1.y & 0xffff0000u);
        qA[(c4 * 2 + 1) * 66 + r] = (t2.x >> 16) | (t3.x & 0xffff0000u);
        qB[(c4 * 2 + 1) * 66 + r] = (t2.y >> 16) | (t3.y & 0xffff0000u);
    }
    __syncthreads();
    int m = lane & 15, qd = lane >> 4;
    f32x4 acc[4];
#pragma unroll
    for (int e = 0; e < 4; ++e) acc[e] = (f32x4){0.f, 0.f, 0.f, 0.f};
#pragma unroll
    for (int kk = 0; kk < 2; ++kk) {
        U8 fa1, fa2;
#pragma unroll
        for (int jp = 0; jp < 4; ++jp) {
            int idx = (kk * 16 + qd * 4 + jp) * 66 + wv * 16 + m;
            fa1.u[jp] = qA[idx]; fa2.u[jp] = qB[idx];
        }
#pragma unroll
        for (int e = 0; e < 4; ++e) {
            U8 fb1, fb2;
#pragma unroll
            for (int jp = 0; jp < 4; ++jp) {
                int idx = (kk * 16 + qd * 4 + jp) * 66 + e * 16 + m;
                fb1.u[jp] = kvA[idx]; fb2.u[jp] = kvB[idx];
            }
            acc[e] = __builtin_amdgcn_mfma_f32_16x16x32_bf16(fa1.s, fb2.s, acc[e], 0, 0, 0);
            acc[e] = __builtin_amdgcn_mfma_f32_16x16x32_bf16(fa2.s, fb1.s, acc[e], 0, 0, 0);
            acc[e] = __builtin_amdgcn_mfma_f32_16x16x32_bf16(fa1.s, fb1.s, acc[e], 0, 0, 0);
        }
    }
    // epilogue: l = l0 + wv*16 + qd*4 + r ; col = e*16 + m
#pragma unroll
    for (int e = 0; e < 4; ++e)
#pragma unroll
        for (int r = 0; r < 4; ++r) {
            int ll = wv * 16 + qd * 4 + r;
            out[nbase + (long)(l0 + ll) * HD + e * 16 + m] = acc[e][r] * coef[ll];
        }
}

extern "C" void kernel_launch(void* const* d_in, const int* in_sizes, int n_in,
                              void* d_out, int out_size, void* d_ws, size_t ws_size,
                              hipStream_t stream) {
    const float* q = (const float*)d_in[0];
    const float* k = (const float*)d_in[1];
    const float* v = (const float*)d_in[2];
    float* out = (float*)d_out;

    k1_sums<<<dim3(K1B, 1, 2), 256, 0, stream>>>(q, k);
    kred<<<64, 256, 0, stream>>>(0);
    k2_norm<<<dim3(K1B, 1, 2), 256, 0, stream>>>(q, k);
    kred<<<64, 256, 0, stream>>>(1);
    k4_kv<<<dim3(SCHUNKS, NH), 256, 0, stream>>>(k, v);
    k4b_reduce<<<dim3(NH, 4), 256, 0, stream>>>();
    k5_out<<<dim3(L_ / 64, NH), 256, 0, stream>>>(q, out);
}

// Round 3
// 280.953 us; speedup vs baseline: 1.3739x; 1.0412x over previous
//
#include <hip/hip_runtime.h>
#include <math.h>

#define EPS 1e-6f
constexpr int N_ = 4, L_ = 4096, H_ = 16, D_ = 64;
constexpr int NH = N_ * H_;             // 64
constexpr int HD = H_ * D_;             // 1024 floats per (n,l) row
constexpr long NSTRIDE = (long)L_ * HD;
constexpr int SCHUNKS = 16;             // 256 s-rows per kv chunk
constexpr int KSB = 2048;               // streaming blocks per tensor (8 rows each)

typedef __attribute__((ext_vector_type(8))) short short8;
typedef __attribute__((ext_vector_type(4))) float f32x4;

// Scratch device globals. All partial buffers fully written before read each
// call (graph-replay safe); no accumulators -> nothing needs zeroing.
__device__ float g_qsum[NH * D_];
__device__ float g_ksum[NH * D_];
__device__ float g_qnr[NH * D_];
__device__ float g_knc[NH * D_];
__device__ float g_kv[NH * D_ * D_];
__device__ float g_kvpart[(long)SCHUNKS * NH * D_ * D_];   // 16 MB
__device__ float g_kncpart[SCHUNKS * NH * D_];
__device__ float g_ssumpart[SCHUNKS * NH];
__device__ float g_partK[(long)KSB * 1024];                // 8 MB
__device__ float g_partQs[(long)KSB * 1024];               // 8 MB
__device__ float g_partQn[(long)KSB * 1024];               // 8 MB

__device__ __forceinline__ float sigm(float x) {
    return 1.0f / (1.0f + __expf(-x));
}
__device__ __forceinline__ float4 sigm4(float4 x) {
    float4 r;
    r.x = sigm(x.x); r.y = sigm(x.y); r.z = sigm(x.z); r.w = sigm(x.w);
    return r;
}
// sum across the 16-lane group (xor masks < 16 stay inside the group)
__device__ __forceinline__ float red16(float p) {
    p += __shfl_xor(p, 1);
    p += __shfl_xor(p, 2);
    p += __shfl_xor(p, 4);
    p += __shfl_xor(p, 8);
    return p;
}
// RNE round of fp32 bits to bf16, returned high-16-aligned
__device__ __forceinline__ unsigned rne_hi(unsigned xb) {
    return (xb + 0x7fffu + ((xb >> 16) & 1u)) & 0xffff0000u;
}
// split: x ~= h1 + h2 (each bf16), residual <= 2^-17 |x|
__device__ __forceinline__ uint2 split2(float x) {
    unsigned h1 = rne_hi(__float_as_uint(x));
    float r = x - __uint_as_float(h1);
    unsigned h2 = rne_hi(__float_as_uint(r));
    return make_uint2(h1, h2);
}
union U8 { unsigned u[4]; short8 s; };

// ---------------- kA: ksum partials (k pass; 8 independent loads in flight) --
__global__ __launch_bounds__(256, 8) void kA_ksum(const float* __restrict__ k) {
    int t = threadIdx.x;
    long g0 = (long)blockIdx.x * 8;
    const float* p = k + g0 * HD + t * 4;
    float4 x[8];
#pragma unroll
    for (int r = 0; r < 8; ++r) x[r] = *(const float4*)(p + (long)r * HD);
    float ax = 0.f, ay = 0.f, az = 0.f, aw = 0.f;
#pragma unroll
    for (int r = 0; r < 8; ++r) {
        float4 s = sigm4(x[r]);
        ax += s.x; ay += s.y; az += s.z; aw += s.w;
    }
    float4 o = {ax, ay, az, aw};
    *(float4*)&g_partK[((long)blockIdx.x << 10) + t * 4] = o;
}

// ---------------- kB: qsum AND qnr partials in ONE q pass ----------------
// qnr needs only ksum (ready). Thread t owns cols t*4..t*4+4 (head t>>4);
// per-row 64-d dot closed with red16 across the 16 threads of the head.
__global__ __launch_bounds__(256, 8) void kB_q(const float* __restrict__ q) {
    int t = threadIdx.x;
    long g0 = (long)blockIdx.x * 8;
    int n = (int)(g0 >> 12);            // 8 | 4096 so n constant per block
    float4 bv = *(const float4*)(g_ksum + n * 1024 + t * 4);
    bv.x += EPS; bv.y += EPS; bv.z += EPS; bv.w += EPS;
    const float* p = q + g0 * HD + t * 4;
    float4 x[8];
#pragma unroll
    for (int r = 0; r < 8; ++r) x[r] = *(const float4*)(p + (long)r * HD);
    float sx = 0.f, sy = 0.f, sz = 0.f, sw = 0.f;
    float nx = 0.f, ny = 0.f, nz = 0.f, nw = 0.f;
#pragma unroll
    for (int r = 0; r < 8; ++r) {
        float4 s = sigm4(x[r]);
        sx += s.x; sy += s.y; sz += s.z; sw += s.w;
        float pd = (s.x + EPS) * bv.x + (s.y + EPS) * bv.y
                 + (s.z + EPS) * bv.z + (s.w + EPS) * bv.w;
        pd = red16(pd);
        float inv = 1.0f / pd;          // nr for this row
        nx += s.x * inv; ny += s.y * inv; nz += s.z * inv; nw += s.w * inv;
    }
    float4 os = {sx, sy, sz, sw};
    float4 on = {nx, ny, nz, nw};
    *(float4*)&g_partQs[((long)blockIdx.x << 10) + t * 4] = os;
    *(float4*)&g_partQn[((long)blockIdx.x << 10) + t * 4] = on;
}

// ---------------- kred: tree-reduce streaming partials ----------------
// mode 0: g_partK -> g_ksum (grid 32x1). mode 1: Qs->qsum, Qn->qnr (grid 32x2).
__global__ __launch_bounds__(256) void kred(int mode) {
    int t = threadIdx.x, z = blockIdx.y;
    const float* src = (mode == 0) ? g_partK : (z ? g_partQn : g_partQs);
    float* dst = (mode == 0) ? g_ksum : (z ? g_qnr : g_qsum);
    int n = blockIdx.x & 3, cc = blockIdx.x >> 2;
    int c = cc * 128 + (t & 31) * 4;
    int bg = t >> 5;                    // 0..7
    float sx = 0.f, sy = 0.f, sz = 0.f, sw = 0.f;
#pragma unroll 4
    for (int i = 0; i < 64; ++i) {
        long b = n * 512 + bg * 64 + i; // 512 blocks per n
        float4 p = *(const float4*)&src[(b << 10) + c];
        sx += p.x; sy += p.y; sz += p.z; sw += p.w;
    }
    __shared__ float4 esb[256];
    esb[t] = make_float4(sx, sy, sz, sw);
    __syncthreads();
    if (t < 32) {
        float4 s = esb[t];
#pragma unroll
        for (int g = 1; g < 8; ++g) {
            float4 b2 = esb[t + g * 32];
            s.x += b2.x; s.y += b2.y; s.z += b2.z; s.w += b2.w;
        }
        *(float4*)&dst[n * 1024 + cc * 128 + t * 4] = s;
    }
}

// ---------------- k4: fused nc+knc+cr+exp+ssum + split2-bf16 MFMA kv ---------
// LDS planes: u32 at [s-pair][col] = {lo16 = bf16(even s), hi16 = bf16(odd s)}
// kA/kB = split1/2 of sig(k)*e_s ; vA/vB = split1/2 of v.
// Also accumulates knc (needs qsum) and ssum as per-chunk partials.
__global__ __launch_bounds__(256, 4) void k4_kv(const float* __restrict__ k,
                                                const float* __restrict__ v) {
    int nh = blockIdx.y, n = nh >> 4, h = nh & 15;
    int t = threadIdx.x, lane = t & 63, wv = t >> 6;
    __shared__ unsigned kA[16 * 66], kB[16 * 66], vA[16 * 66], vB[16 * 66];
    __shared__ float kncred[16 * 64];
    __shared__ float esb[256];
    int sp = t >> 4, c4 = t & 15;
    long nbase = (long)n * NSTRIDE + (long)h * D_;
    int s0blk = blockIdx.x * 256;
    float4 qn = *(const float4*)&g_qnr[nh * 64 + c4 * 4];
    qn.x += EPS; qn.y += EPS; qn.z += EPS; qn.w += EPS;
    float4 qs = *(const float4*)&g_qsum[nh * 64 + c4 * 4];
    qs.x += EPS; qs.y += EPS; qs.z += EPS; qs.w += EPS;

    f32x4 acc[4];
#pragma unroll
    for (int e = 0; e < 4; ++e) acc[e] = (f32x4){0.f, 0.f, 0.f, 0.f};
    int m = lane & 15, qd = lane >> 4;
    float esum = 0.f;
    float knx = 0.f, kny = 0.f, knz = 0.f, knw = 0.f;

    float4 ke, ko, ve, vo;
    {
        long gb = nbase + (long)(s0blk + 2 * sp) * HD + c4 * 4;
        ke = *(const float4*)&k[gb]; ko = *(const float4*)&k[gb + HD];
        ve = *(const float4*)&v[gb]; vo = *(const float4*)&v[gb + HD];
    }
    for (int st = 0; st < 8; ++st) {
        // ---- sigm + nc/cr dots + exp + knc + scale + pack (registers only)
        float4 se = sigm4(ke), so = sigm4(ko);
        float pde = (se.x + EPS) * qn.x + (se.y + EPS) * qn.y
                  + (se.z + EPS) * qn.z + (se.w + EPS) * qn.w;
        float pdo = (so.x + EPS) * qn.x + (so.y + EPS) * qn.y
                  + (so.z + EPS) * qn.z + (so.w + EPS) * qn.w;
        float pne = (se.x + EPS) * qs.x + (se.y + EPS) * qs.y
                  + (se.z + EPS) * qs.z + (se.w + EPS) * qs.w;
        float pno = (so.x + EPS) * qs.x + (so.y + EPS) * qs.y
                  + (so.z + EPS) * qs.z + (so.w + EPS) * qs.w;
        pde = red16(pde); pdo = red16(pdo);
        pne = red16(pne); pno = red16(pno);
        float ee = __expf(pde), eo = __expf(pdo);
        if (c4 == 0) esum += ee + eo;
        float nce = 1.0f / pne, nco = 1.0f / pno;
        knx += se.x * nce + so.x * nco;
        kny += se.y * nce + so.y * nco;
        knz += se.z * nce + so.z * nco;
        knw += se.w * nce + so.w * nco;
        se.x *= ee; se.y *= ee; se.z *= ee; se.w *= ee;
        so.x *= eo; so.y *= eo; so.z *= eo; so.w *= eo;
        uint2 a0 = split2(se.x), a1_ = split2(se.y), a2_ = split2(se.z), a3_ = split2(se.w);
        uint2 b0 = split2(so.x), b1_ = split2(so.y), b2_ = split2(so.z), b3_ = split2(so.w);
        unsigned kaw0 = (a0.x >> 16) | (b0.x & 0xffff0000u);
        unsigned kaw1 = (a1_.x >> 16) | (b1_.x & 0xffff0000u);
        unsigned kaw2 = (a2_.x >> 16) | (b2_.x & 0xffff0000u);
        unsigned kaw3 = (a3_.x >> 16) | (b3_.x & 0xffff0000u);
        unsigned kbw0 = (a0.y >> 16) | (b0.y & 0xffff0000u);
        unsigned kbw1 = (a1_.y >> 16) | (b1_.y & 0xffff0000u);
        unsigned kbw2 = (a2_.y >> 16) | (b2_.y & 0xffff0000u);
        unsigned kbw3 = (a3_.y >> 16) | (b3_.y & 0xffff0000u);
        uint2 c0 = split2(ve.x), c1 = split2(ve.y), c2 = split2(ve.z), c3 = split2(ve.w);
        uint2 d0 = split2(vo.x), d1 = split2(vo.y), d2 = split2(vo.z), d3 = split2(vo.w);
        unsigned vaw0 = (c0.x >> 16) | (d0.x & 0xffff0000u);
        unsigned vaw1 = (c1.x >> 16) | (d1.x & 0xffff0000u);
        unsigned vaw2 = (c2.x >> 16) | (d2.x & 0xffff0000u);
        unsigned vaw3 = (c3.x >> 16) | (d3.x & 0xffff0000u);
        unsigned vbw0 = (c0.y >> 16) | (d0.y & 0xffff0000u);
        unsigned vbw1 = (c1.y >> 16) | (d1.y & 0xffff0000u);
        unsigned vbw2 = (c2.y >> 16) | (d2.y & 0xffff0000u);
        unsigned vbw3 = (c3.y >> 16) | (d3.y & 0xffff0000u);
        __syncthreads();   // prior MFMA reads done
        int wb = sp * 66 + c4 * 4;
        *(uint2*)&kA[wb] = make_uint2(kaw0, kaw1); *(uint2*)&kA[wb + 2] = make_uint2(kaw2, kaw3);
        *(uint2*)&kB[wb] = make_uint2(kbw0, kbw1); *(uint2*)&kB[wb + 2] = make_uint2(kbw2, kbw3);
        *(uint2*)&vA[wb] = make_uint2(vaw0, vaw1); *(uint2*)&vA[wb + 2] = make_uint2(vaw2, vaw3);
        *(uint2*)&vB[wb] = make_uint2(vbw0, vbw1); *(uint2*)&vB[wb + 2] = make_uint2(vbw2, vbw3);
        __syncthreads();
        if (st < 7) {      // prefetch next subtile under the MFMA phase
            long gb = nbase + (long)(s0blk + (st + 1) * 32 + 2 * sp) * HD + c4 * 4;
            ke = *(const float4*)&k[gb]; ko = *(const float4*)&k[gb + HD];
            ve = *(const float4*)&v[gb]; vo = *(const float4*)&v[gb + HD];
        }
        // ---- MFMA: one K=32 step over these 32 s-rows
        U8 fa1, fa2;
#pragma unroll
        for (int jp = 0; jp < 4; ++jp) {
            int idx = (qd * 4 + jp) * 66 + wv * 16 + m;
            fa1.u[jp] = kA[idx]; fa2.u[jp] = kB[idx];
        }
#pragma unroll
        for (int e = 0; e < 4; ++e) {
            U8 fb1, fb2;
#pragma unroll
            for (int jp = 0; jp < 4; ++jp) {
                int idx = (qd * 4 + jp) * 66 + e * 16 + m;
                fb1.u[jp] = vA[idx]; fb2.u[jp] = vB[idx];
            }
            acc[e] = __builtin_amdgcn_mfma_f32_16x16x32_bf16(fa1.s, fb2.s, acc[e], 0, 0, 0);
            acc[e] = __builtin_amdgcn_mfma_f32_16x16x32_bf16(fa2.s, fb1.s, acc[e], 0, 0, 0);
            acc[e] = __builtin_amdgcn_mfma_f32_16x16x32_bf16(fa1.s, fb1.s, acc[e], 0, 0, 0);
        }
    }
    // epilogue: C/D layout col=lane&15, row=qd*4+reg; wave wv owns d-strip
    float* dst = &g_kvpart[((long)blockIdx.x * NH + nh) * 4096];
#pragma unroll
    for (int e = 0; e < 4; ++e)
#pragma unroll
        for (int r = 0; r < 4; ++r)
            dst[(wv * 16 + qd * 4 + r) * 64 + e * 16 + m] = acc[e][r];
    // knc partial: reduce over the 16 sp row-groups
    *(float4*)&kncred[sp * 64 + c4 * 4] = make_float4(knx, kny, knz, knw);
    esb[t] = esum;
    __syncthreads();
    if (t < 64) {
        float s = 0.f;
#pragma unroll
        for (int i = 0; i < 16; ++i) s += kncred[i * 64 + t];
        g_kncpart[(blockIdx.x * NH + nh) * 64 + t] = s;
    }
    for (int s2 = 128; s2; s2 >>= 1) {
        if (t < s2) esb[t] += esb[t + s2];
        __syncthreads();
    }
    if (t == 0) g_ssumpart[blockIdx.x * NH + nh] = esb[0];
}

// ---------------- k4b: reduce kv partials (scale), knc partials ----------------
__global__ __launch_bounds__(256) void k4b_reduce() {
    int nh = blockIdx.x, t = threadIdx.x;
    float ssum = 0.f;
#pragma unroll
    for (int c = 0; c < SCHUNKS; ++c) ssum += g_ssumpart[c * NH + nh];
    float scale = (float)L_ / ssum;
    int i4 = blockIdx.y * 256 + t;      // float4 index 0..1023
    float sx = 0.f, sy = 0.f, sz = 0.f, sw = 0.f;
#pragma unroll
    for (int c = 0; c < SCHUNKS; ++c) {
        float4 p = *(const float4*)&g_kvpart[((long)c * NH + nh) * 4096 + i4 * 4];
        sx += p.x; sy += p.y; sz += p.z; sw += p.w;
    }
    float4 o = {sx * scale, sy * scale, sz * scale, sw * scale};
    *(float4*)&g_kv[nh * 4096 + i4 * 4] = o;
    if (blockIdx.y == 0 && t < 64) {
        float s = 0.f;
#pragma unroll
        for (int c = 0; c < SCHUNKS; ++c) s += g_kncpart[(c * NH + nh) * 64 + t];
        g_knc[nh * 64 + t] = s;
    }
}

// ---------------- k5: inline coef + split2-bf16 MFMA out = sig(q)@kv * coef ---
__global__ __launch_bounds__(256, 4) void k5_out(const float* __restrict__ q,
                                                 float* __restrict__ out) {
    int nh = blockIdx.y, n = nh >> 4, h = nh & 15;
    int t = threadIdx.x, lane = t & 63, wv = t >> 6;
    __shared__ unsigned qA[32 * 66], qB[32 * 66], kvA[32 * 66], kvB[32 * 66];
    __shared__ float coef[64];
    int c4 = t & 15;
    long nbase = (long)n * NSTRIDE + (long)h * D_;
    int l0 = blockIdx.x * 64;
    float4 bk1 = *(const float4*)&g_ksum[nh * 64 + c4 * 4];
    float4 bk2 = *(const float4*)&g_knc[nh * 64 + c4 * 4];
    bk1.x += EPS; bk1.y += EPS; bk1.z += EPS; bk1.w += EPS;
    bk2.x += EPS; bk2.y += EPS; bk2.z += EPS; bk2.w += EPS;
    // hoist ALL staging loads (8 independent in flight)
    float4 xe[2], xo[2];
#pragma unroll
    for (int j = 0; j < 2; ++j) {
        int slot = t + j * 256;
        int dp = slot >> 4, cc = slot & 15;
        const float* kvr = &g_kv[nh * 4096 + (2 * dp) * 64 + cc * 4];
        xe[j] = *(const float4*)kvr;
        xo[j] = *(const float4*)(kvr + 64);
    }
    float4 xq[4];
#pragma unroll
    for (int j = 0; j < 4; ++j) {
        int r = (t >> 4) + j * 16;
        xq[j] = *(const float4*)&q[nbase + (long)(l0 + r) * HD + c4 * 4];
    }
    // stage kv (pair-packed over d)
#pragma unroll
    for (int j = 0; j < 2; ++j) {
        int slot = t + j * 256;
        int dp = slot >> 4, cc = slot & 15;
        uint2 e0 = split2(xe[j].x), e1 = split2(xe[j].y), e2 = split2(xe[j].z), e3 = split2(xe[j].w);
        uint2 o0 = split2(xo[j].x), o1 = split2(xo[j].y), o2 = split2(xo[j].z), o3 = split2(xo[j].w);
        int wb = dp * 66 + cc * 4;
        *(uint2*)&kvA[wb] = make_uint2((e0.x >> 16) | (o0.x & 0xffff0000u),
                                       (e1.x >> 16) | (o1.x & 0xffff0000u));
        *(uint2*)&kvA[wb + 2] = make_uint2((e2.x >> 16) | (o2.x & 0xffff0000u),
                                           (e3.x >> 16) | (o3.x & 0xffff0000u));
        *(uint2*)&kvB[wb] = make_uint2((e0.y >> 16) | (o0.y & 0xffff0000u),
                                       (e1.y >> 16) | (o1.y & 0xffff0000u));
        *(uint2*)&kvB[wb + 2] = make_uint2((e2.y >> 16) | (o2.y & 0xffff0000u),
                                           (e3.y >> 16) | (o3.y & 0xffff0000u));
    }
    // stage q (pair-packed over d, transposed to [dp][l]) + coef
#pragma unroll
    for (int j = 0; j < 4; ++j) {
        int r = (t >> 4) + j * 16;
        float4 s = sigm4(xq[j]);
        float p1 = (s.x + EPS) * bk1.x + (s.y + EPS) * bk1.y
                 + (s.z + EPS) * bk1.z + (s.w + EPS) * bk1.w;
        float p2 = (s.x + EPS) * bk2.x + (s.y + EPS) * bk2.y
                 + (s.z + EPS) * bk2.z + (s.w + EPS) * bk2.w;
        p1 = red16(p1); p2 = red16(p2);
        if (c4 == 0) coef[r] = sigm(p2) / p1;
        uint2 t0 = split2(s.x), t1 = split2(s.y), t2 = split2(s.z), t3 = split2(s.w);
        qA[(c4 * 2) * 66 + r]     = (t0.x >> 16) | (t1.x & 0xffff0000u);
        qB[(c4 * 2) * 66 + r]     = (t0.y >> 16) | (t1.y & 0xffff0000u);
        qA[(c4 * 2 + 1) * 66 + r] = (t2.x >> 16) | (t3.x & 0xffff0000u);
        qB[(c4 * 2 + 1) * 66 + r] = (t2.y >> 16) | (t3.y & 0xffff0000u);
    }
    __syncthreads();
    int m = lane & 15, qd = lane >> 4;
    f32x4 acc[4];
#pragma unroll
    for (int e = 0; e < 4; ++e) acc[e] = (f32x4){0.f, 0.f, 0.f, 0.f};
#pragma unroll
    for (int kk = 0; kk < 2; ++kk) {
        U8 fa1, fa2;
#pragma unroll
        for (int jp = 0; jp < 4; ++jp) {
            int idx = (kk * 16 + qd * 4 + jp) * 66 + wv * 16 + m;
            fa1.u[jp] = qA[idx]; fa2.u[jp] = qB[idx];
        }
#pragma unroll
        for (int e = 0; e < 4; ++e) {
            U8 fb1, fb2;
#pragma unroll
            for (int jp = 0; jp < 4; ++jp) {
                int idx = (kk * 16 + qd * 4 + jp) * 66 + e * 16 + m;
                fb1.u[jp] = kvA[idx]; fb2.u[jp] = kvB[idx];
            }
            acc[e] = __builtin_amdgcn_mfma_f32_16x16x32_bf16(fa1.s, fb2.s, acc[e], 0, 0, 0);
            acc[e] = __builtin_amdgcn_mfma_f32_16x16x32_bf16(fa2.s, fb1.s, acc[e], 0, 0, 0);
            acc[e] = __builtin_amdgcn_mfma_f32_16x16x32_bf16(fa1.s, fb1.s, acc[e], 0, 0, 0);
        }
    }
    // epilogue: l = l0 + wv*16 + qd*4 + r ; col = e*16 + m
#pragma unroll
    for (int e = 0; e < 4; ++e)
#pragma unroll
        for (int r = 0; r < 4; ++r) {
            int ll = wv * 16 + qd * 4 + r;
            out[nbase + (long)(l0 + ll) * HD + e * 16 + m] = acc[e][r] * coef[ll];
        }
}

extern "C" void kernel_launch(void* const* d_in, const int* in_sizes, int n_in,
                              void* d_out, int out_size, void* d_ws, size_t ws_size,
                              hipStream_t stream) {
    const float* q = (const float*)d_in[0];
    const float* k = (const float*)d_in[1];
    const float* v = (const float*)d_in[2];
    float* out = (float*)d_out;

    kA_ksum<<<KSB, 256, 0, stream>>>(k);
    kred<<<dim3(32, 1), 256, 0, stream>>>(0);
    kB_q<<<KSB, 256, 0, stream>>>(q);
    kred<<<dim3(32, 2), 256, 0, stream>>>(1);
    k4_kv<<<dim3(SCHUNKS, NH), 256, 0, stream>>>(k, v);
    k4b_reduce<<<dim3(NH, 4), 256, 0, stream>>>();
    k5_out<<<dim3(L_ / 64, NH), 256, 0, stream>>>(q, out);
}